// Round 9
// baseline (166.413 us; speedup 1.0000x reference)
//
#include <hip/hip_runtime.h>
#include <stdint.h>

typedef unsigned short u16;
typedef __attribute__((ext_vector_type(8))) __bf16 bf16x8;
typedef __attribute__((ext_vector_type(4))) float f32x4;
typedef __attribute__((ext_vector_type(4))) u16 u16x4;
typedef __attribute__((ext_vector_type(8))) u16 u16x8;

#define N_IMG 64
#define C_IN  64
#define HW_IN 3136   // 56*56
#define W_IN  56
#define C_OUT 128
#define OH    54
#define OW    54
#define SPI   2916   // 54*54
#define KTOT  576    // C_IN*9
#define SP_BLK 128   // output positions per block
#define NBPI  23     // ceil(SPI/128)
#define NWG   (N_IMG*NBPI)   // 1472 = 8*184
#define SLAB_ROWS 256 // need <=248 (133 intra span + 114 tap + 1); 256 = 8 clean rounds

typedef __attribute__((address_space(3))) unsigned int lds_uint;
typedef __attribute__((address_space(1))) unsigned int gbl_uint;

__device__ __forceinline__ void load16_to_lds(const u16* g, u16* l) {
  // lane i of the wave writes LDS base + i*16 bytes; g is per-lane.
  __builtin_amdgcn_global_load_lds((const gbl_uint*)g, (lds_uint*)l, 16, 0, 0);
}

__device__ inline u16 f32_bf16_rne(float f) {
  unsigned u = __float_as_uint(f);
  u = (u + 0x7FFFu + ((u >> 16) & 1u)) >> 16;
  return (u16)u;
}

// Merged converter (unchanged).
__global__ __launch_bounds__(256) void convert_xw(
    const float* __restrict__ x, const float* __restrict__ w,
    u16* __restrict__ xt, u16* __restrict__ wtT)
{
  if (blockIdx.y == N_IMG) {
    int o = blockIdx.x * 256 + threadIdx.x;
    for (; o < C_OUT * KTOT; o += 49 * 256) {
      int co = o / KTOT;
      int k  = o - co * KTOT;
      int t  = k >> 6;       // kh*3+kw
      int ci = k & 63;
      wtT[o] = f32_bf16_rne(w[co * KTOT + ci * 9 + t]);
    }
    return;
  }

  __shared__ u16 tile[64][68];
  int n  = blockIdx.y;
  int s0 = blockIdx.x * 64;
  int t  = threadIdx.x;

  int r = t >> 2;
  int q = t & 3;
  const float* xp = x + (size_t)n * C_IN * HW_IN + (size_t)r * HW_IN + s0 + q * 16;
  #pragma unroll
  for (int j = 0; j < 4; j++) {
    f32x4 v = *(const f32x4*)(xp + 4 * j);
    u16x4 o4;
    #pragma unroll
    for (int e = 0; e < 4; e++) {
      float f = fminf(fmaxf(v[e], -128.f), 127.f);
      int iv = (int)f;
      o4[e] = f32_bf16_rne((float)iv);
    }
    *(u16x4*)&tile[r][q * 16 + 4 * j] = o4;
  }
  __syncthreads();

  u16* op = xt + ((size_t)n * HW_IN + s0) * C_IN;
  int g = t & 7;
  int m = t >> 3;
  #pragma unroll
  for (int k2 = 0; k2 < 2; k2++) {
    int sp = m * 2 + k2;
    u16x8 o8;
    #pragma unroll
    for (int c = 0; c < 8; c++) o8[c] = tile[g * 8 + c][sp];
    *(u16x8*)&op[(size_t)sp * C_IN + g * 8] = o8;
  }
}

// Implicit GEMM, COUNTED-VMCNT RING schedule (T3+T4 port).
// Block = 128 spatial x 128 cout of ONE image, 4 waves, wave tile 64co x 64sp.
// Pixels: 32 KB halo slab staged ONCE (all 9 taps = row offsets).
// Weights: 3-slot LDS ring (3 x 16 KB); tap kc+2's loads issued during tap kc.
// Each tap: s_waitcnt vmcnt(4) (retires exactly tap-kc's 4 loads/thread,
// issued TWO phases earlier -> ~already landed) + RAW s_barrier. vmcnt never
// drains to 0 in the loop (only the kc==8 tail). This removes the 9 full
// vmcnt(0)+lgkmcnt(0) drains that __syncthreads() imposed (m233: that drain is
// ~72% of a 2-phase loop's critical path; rounds 3/7/8 all ~44-46 us because
// they share it). Ring WAR safety: slot kc%3 last read at tap kc-3; those
// ds_reads retire before barrier kc-2; overwrite DMA issues after it.
// LDS = 32 + 48 = 80 KB exactly -> 2 blocks/CU (8 waves/CU).
__global__ __launch_bounds__(256, 2) void conv_gemm(
    const u16* __restrict__ xt, const u16* __restrict__ wtT,
    const float* __restrict__ bias, float* __restrict__ y)
{
  __shared__ u16 slab[SLAB_ROWS * 64];  // 32 KB pixel slab (swizzled ci-groups)
  __shared__ u16 sW[3][128 * 64];       // 48 KB weight ring

  int tid  = threadIdx.x;
  int wv   = tid >> 6;           // 0..3
  int lane = tid & 63;
  int ln   = lane & 15;
  int q    = lane >> 4;
  int wy   = wv >> 1;            // cout half (64 rows)
  int wx   = wv & 1;             // spatial half (64 cols)

  // XCD-aware swizzle: 1472 = 8*184 exactly
  int b  = blockIdx.x;
  int wg = (b & 7) * (NWG / 8) + (b >> 3);
  int img = wg / NBPI;
  int cb  = wg - img * NBPI;
  int r0  = cb * SP_BLK;                 // first output position (image-local)
  int ibase = r0 + 2 * (r0 / OW);        // slab base input position

  const u16* xti = xt + (size_t)img * HW_IN * C_IN;

  // staging lane mapping: slot = j*256 + tid -> row = j*32 + (tid>>3), grp tid&7
  int trow = tid >> 3;           // 0..31
  int cg   = tid & 7;

  // ---- prologue staging (order matters for the vmcnt accounting):
  // 8 slab rounds, then W tap0 (4), then W tap1 (4) = 16 loads/thread.
  #pragma unroll
  for (int j = 0; j < 8; j++) {
    int row  = j * 32 + trow;
    int grow = ibase + row;
    if (grow > HW_IN - 1) grow = HW_IN - 1;   // clamp: feeds only dead outputs
    load16_to_lds(xti + (size_t)grow * 64 + ((cg ^ (row & 7)) * 8),
                  slab + (size_t)(j * 256 + wv * 64) * 8);
  }
  int wt_base[4];
  #pragma unroll
  for (int j = 0; j < 4; j++) {
    int row = j * 32 + trow;                   // cout row 0..127
    wt_base[j] = row * KTOT + ((cg ^ (row & 7)) * 8);
  }
  #pragma unroll
  for (int j = 0; j < 4; j++)                  // W tap 0 -> slot 0
    load16_to_lds(wtT + wt_base[j], &sW[0][(j * 256 + wv * 64) * 8]);
  #pragma unroll
  for (int j = 0; j < 4; j++)                  // W tap 1 -> slot 1
    load16_to_lds(wtT + wt_base[j] + 64, &sW[1][(j * 256 + wv * 64) * 8]);

  f32x4 acc[4][4];
  #pragma unroll
  for (int mt = 0; mt < 4; mt++)
    #pragma unroll
    for (int nt = 0; nt < 4; nt++)
      acc[mt][nt] = (f32x4){0.f, 0.f, 0.f, 0.f};

  // per-lane output positions and slab base rows (tap (0,0))
  int prel[4], rbase[4];
  #pragma unroll
  for (int nt = 0; nt < 4; nt++) {
    int pr = r0 + wx * 64 + nt * 16 + ln;
    prel[nt]  = pr;
    rbase[nt] = pr + 2 * (pr / OW) - ibase;    // 0..133
  }
  int wrow[4];
  #pragma unroll
  for (int mt = 0; mt < 4; mt++) wrow[mt] = wy * 64 + mt * 16 + ln;   // cout row

  #pragma unroll
  for (int kc = 0; kc < 9; kc++) {
    const int slot = kc % 3;
    const int kh = kc / 3, kw = kc - kh * 3;
    const int koff = kh * W_IN + kw;           // slab row offset of this tap

    // counted wait: my 4 loads for tap kc (issued 2 phases ago) retired;
    // tap kc+1's 4 stay in flight. Then raw barrier -> ALL waves' kc loads
    // are in LDS. sched_barrier stops ds_reads hoisting above the barrier.
    if (kc == 8) asm volatile("s_waitcnt vmcnt(0)" ::: "memory");
    else         asm volatile("s_waitcnt vmcnt(4)" ::: "memory");
    __builtin_amdgcn_s_barrier();
    __builtin_amdgcn_sched_barrier(0);

    #pragma unroll
    for (int si = 0; si < 2; si++) {
      int gg = si * 4 + q;                     // ci 8-group within the tap
      bf16x8 wf[4], pf[4];
      #pragma unroll
      for (int mt = 0; mt < 4; mt++) {
        int co = wrow[mt];
        wf[mt] = *(const bf16x8*)(&sW[slot][0] + co * 64 + ((gg ^ (co & 7)) * 8));
      }
      #pragma unroll
      for (int nt = 0; nt < 4; nt++) {
        int rb = rbase[nt] + koff;             // slab row for this lane+tap
        pf[nt] = *(const bf16x8*)(slab + rb * 64 + ((gg ^ (rb & 7)) * 8));
      }

      // issue tap kc+2's W loads mid-phase (slot kc+2 mod 3: safe, its readers
      // at tap kc-1 retired before this tap's barrier)
      if (si == 0 && kc < 7) {
        #pragma unroll
        for (int j = 0; j < 4; j++)
          load16_to_lds(wtT + wt_base[j] + (kc + 2) * 64,
                        &sW[(kc + 2) % 3][(j * 256 + wv * 64) * 8]);
      }

      __builtin_amdgcn_s_setprio(1);
      #pragma unroll
      for (int mt = 0; mt < 4; mt++)
        #pragma unroll
        for (int nt = 0; nt < 4; nt++)
          acc[mt][nt] = __builtin_amdgcn_mfma_f32_16x16x32_bf16(
              wf[mt], pf[nt], acc[mt][nt], 0, 0, 0);
      __builtin_amdgcn_s_setprio(0);
    }
  }

  // epilogue: y is [img][co][p_rel]; mask dead tail positions
  size_t obase0 = (size_t)img * C_OUT * SPI;
  #pragma unroll
  for (int nt = 0; nt < 4; nt++) {
    int pr = prel[nt];
    if (pr < SPI) {
      #pragma unroll
      for (int mt = 0; mt < 4; mt++) {
        int co0 = wy * 64 + mt * 16 + q * 4;
        #pragma unroll
        for (int r = 0; r < 4; r++)
          y[obase0 + (size_t)(co0 + r) * SPI + pr] = acc[mt][nt][r] + bias[co0 + r];
      }
    }
  }
}

extern "C" void kernel_launch(void* const* d_in, const int* in_sizes, int n_in,
                              void* d_out, int out_size, void* d_ws, size_t ws_size,
                              hipStream_t stream) {
  const float* x    = (const float*)d_in[0];
  const float* w    = (const float*)d_in[1];
  const float* bias = (const float*)d_in[2];
  float* y = (float*)d_out;

  u16* wtT = (u16*)d_ws;
  u16* xt  = (u16*)((char*)d_ws + (size_t)C_OUT * KTOT * sizeof(u16)); // +147456 B

  hipLaunchKernelGGL(convert_xw, dim3(HW_IN / 64, N_IMG + 1), dim3(256), 0, stream,
                     x, w, xt, wtT);
  hipLaunchKernelGGL(conv_gemm, dim3(NWG), dim3(256), 0, stream,
                     xt, wtT, bias, y);
}

// Round 10
// 159.764 us; speedup vs baseline: 1.0416x; 1.0416x over previous
//
#include <hip/hip_runtime.h>
#include <stdint.h>

typedef unsigned short u16;
typedef __attribute__((ext_vector_type(8))) __bf16 bf16x8;
typedef __attribute__((ext_vector_type(4))) float f32x4;
typedef __attribute__((ext_vector_type(4))) u16 u16x4;
typedef __attribute__((ext_vector_type(8))) u16 u16x8;

#define N_IMG 64
#define C_IN  64
#define HW_IN 3136   // 56*56
#define W_IN  56
#define C_OUT 128
#define OH    54
#define OW    54
#define SPI   2916   // 54*54  (divisible by 4 -> dwordx4 tail mask is exact)
#define KTOT  576    // C_IN*9
#define SP_BLK 128   // output positions per block
#define NBPI  23     // ceil(SPI/128)
#define NWG   (N_IMG*NBPI)   // 1472 = 8*184
#define SLAB_ROWS 256

typedef __attribute__((address_space(3))) unsigned int lds_uint;
typedef __attribute__((address_space(1))) unsigned int gbl_uint;

__device__ __forceinline__ void load16_to_lds(const u16* g, u16* l) {
  // lane i of the wave writes LDS base + i*16 bytes; g is per-lane.
  __builtin_amdgcn_global_load_lds((const gbl_uint*)g, (lds_uint*)l, 16, 0, 0);
}

__device__ inline u16 f32_bf16_rne(float f) {
  unsigned u = __float_as_uint(f);
  u = (u + 0x7FFFu + ((u >> 16) & 1u)) >> 16;
  return (u16)u;
}

// Merged converter (unchanged).
__global__ __launch_bounds__(256) void convert_xw(
    const float* __restrict__ x, const float* __restrict__ w,
    u16* __restrict__ xt, u16* __restrict__ wtT)
{
  if (blockIdx.y == N_IMG) {
    int o = blockIdx.x * 256 + threadIdx.x;
    for (; o < C_OUT * KTOT; o += 49 * 256) {
      int co = o / KTOT;
      int k  = o - co * KTOT;
      int t  = k >> 6;       // kh*3+kw
      int ci = k & 63;
      wtT[o] = f32_bf16_rne(w[co * KTOT + ci * 9 + t]);
    }
    return;
  }

  __shared__ u16 tile[64][68];
  int n  = blockIdx.y;
  int s0 = blockIdx.x * 64;
  int t  = threadIdx.x;

  int r = t >> 2;
  int q = t & 3;
  const float* xp = x + (size_t)n * C_IN * HW_IN + (size_t)r * HW_IN + s0 + q * 16;
  #pragma unroll
  for (int j = 0; j < 4; j++) {
    f32x4 v = *(const f32x4*)(xp + 4 * j);
    u16x4 o4;
    #pragma unroll
    for (int e = 0; e < 4; e++) {
      float f = fminf(fmaxf(v[e], -128.f), 127.f);
      int iv = (int)f;
      o4[e] = f32_bf16_rne((float)iv);
    }
    *(u16x4*)&tile[r][q * 16 + 4 * j] = o4;
  }
  __syncthreads();

  u16* op = xt + ((size_t)n * HW_IN + s0) * C_IN;
  int g = t & 7;
  int m = t >> 3;
  #pragma unroll
  for (int k2 = 0; k2 < 2; k2++) {
    int sp = m * 2 + k2;
    u16x8 o8;
    #pragma unroll
    for (int c = 0; c < 8; c++) o8[c] = tile[g * 8 + c][sp];
    *(u16x8*)&op[(size_t)sp * C_IN + g * 8] = o8;
  }
}

// Implicit GEMM, r9 counted-vmcnt ring K-loop + TRANSPOSED VECTOR EPILOGUE.
// Rounds 3-9 proved schedule & LDS-volume changes don't move conv_gemm
// (~44-49 us across every variant). The invariant in all rounds: the output
// path - 64 scalar 4B stores/thread, 64B quarter-wave runs, WRITE_SIZE 124 MB
// vs 96 ideal (1.3x partial-line amplification), ~3 TB/s effective vs 6.8
// that pure sequential writes reach on this chip. Round-10 change: after the
// K-loop, each wave transposes its 64co x 64sp accumulator through a private
// 16 KB patch of the (dead) slab/sW LDS and stores dwordx4 256B-contiguous
// full lines. LDS roundtrip ~3 us vs predicted ~15 us write-path win.
__global__ __launch_bounds__(256, 2) void conv_gemm(
    const u16* __restrict__ xt, const u16* __restrict__ wtT,
    const float* __restrict__ bias, float* __restrict__ y)
{
  __shared__ u16 smem[40960];           // 80 KB: [0,32K)=slab, [32K,80K)=W ring
  u16* slab = smem;                     // 32 KB pixel slab (swizzled ci-groups)
  #define SW(slot) (smem + 16384 + (slot) * 8192)   // 16 KB W ring slots

  int tid  = threadIdx.x;
  int wv   = tid >> 6;           // 0..3
  int lane = tid & 63;
  int ln   = lane & 15;
  int q    = lane >> 4;
  int wy   = wv >> 1;            // cout half (64 rows)
  int wx   = wv & 1;             // spatial half (64 cols)

  // XCD-aware swizzle: 1472 = 8*184 exactly
  int b  = blockIdx.x;
  int wg = (b & 7) * (NWG / 8) + (b >> 3);
  int img = wg / NBPI;
  int cb  = wg - img * NBPI;
  int r0  = cb * SP_BLK;                 // first output position (image-local)
  int ibase = r0 + 2 * (r0 / OW);        // slab base input position

  const u16* xti = xt + (size_t)img * HW_IN * C_IN;

  int trow = tid >> 3;           // 0..31
  int cg   = tid & 7;

  // ---- prologue staging: 8 slab rounds, then W tap0, W tap1 (16 loads/thr).
  #pragma unroll
  for (int j = 0; j < 8; j++) {
    int row  = j * 32 + trow;
    int grow = ibase + row;
    if (grow > HW_IN - 1) grow = HW_IN - 1;   // clamp: feeds only dead outputs
    load16_to_lds(xti + (size_t)grow * 64 + ((cg ^ (row & 7)) * 8),
                  slab + (size_t)(j * 256 + wv * 64) * 8);
  }
  int wt_base[4];
  #pragma unroll
  for (int j = 0; j < 4; j++) {
    int row = j * 32 + trow;                   // cout row 0..127
    wt_base[j] = row * KTOT + ((cg ^ (row & 7)) * 8);
  }
  #pragma unroll
  for (int j = 0; j < 4; j++)                  // W tap 0 -> slot 0
    load16_to_lds(wtT + wt_base[j], SW(0) + (j * 256 + wv * 64) * 8);
  #pragma unroll
  for (int j = 0; j < 4; j++)                  // W tap 1 -> slot 1
    load16_to_lds(wtT + wt_base[j] + 64, SW(1) + (j * 256 + wv * 64) * 8);

  // bias fragment for this lane's 16 cout values (L2-hot, once per block)
  float bs[4][4];
  #pragma unroll
  for (int mt = 0; mt < 4; mt++)
    #pragma unroll
    for (int r = 0; r < 4; r++)
      bs[mt][r] = bias[wy * 64 + mt * 16 + q * 4 + r];

  f32x4 acc[4][4];
  #pragma unroll
  for (int mt = 0; mt < 4; mt++)
    #pragma unroll
    for (int nt = 0; nt < 4; nt++)
      acc[mt][nt] = (f32x4){0.f, 0.f, 0.f, 0.f};

  int rbase[4];
  #pragma unroll
  for (int nt = 0; nt < 4; nt++) {
    int pr = r0 + wx * 64 + nt * 16 + ln;
    rbase[nt] = pr + 2 * (pr / OW) - ibase;    // 0..133
  }
  int wrow[4];
  #pragma unroll
  for (int mt = 0; mt < 4; mt++) wrow[mt] = wy * 64 + mt * 16 + ln;   // cout row

  #pragma unroll
  for (int kc = 0; kc < 9; kc++) {
    const int slot = kc % 3;
    const int kh = kc / 3, kw = kc - kh * 3;
    const int koff = kh * W_IN + kw;           // slab row offset of this tap

    // counted wait: my 4 loads for tap kc (issued 2 phases ago) retired;
    // tap kc+1's stay in flight. Raw barrier -> all waves' kc loads in LDS.
    if (kc == 8) asm volatile("s_waitcnt vmcnt(0)" ::: "memory");
    else         asm volatile("s_waitcnt vmcnt(4)" ::: "memory");
    __builtin_amdgcn_s_barrier();
    __builtin_amdgcn_sched_barrier(0);

    #pragma unroll
    for (int si = 0; si < 2; si++) {
      int gg = si * 4 + q;                     // ci 8-group within the tap
      bf16x8 wf[4], pf[4];
      #pragma unroll
      for (int mt = 0; mt < 4; mt++) {
        int co = wrow[mt];
        wf[mt] = *(const bf16x8*)(SW(slot) + co * 64 + ((gg ^ (co & 7)) * 8));
      }
      #pragma unroll
      for (int nt = 0; nt < 4; nt++) {
        int rb = rbase[nt] + koff;             // slab row for this lane+tap
        pf[nt] = *(const bf16x8*)(slab + rb * 64 + ((gg ^ (rb & 7)) * 8));
      }

      // issue tap kc+2's W loads mid-phase (ring slot safe: its readers
      // retired before this tap's barrier)
      if (si == 0 && kc < 7) {
        #pragma unroll
        for (int j = 0; j < 4; j++)
          load16_to_lds(wtT + wt_base[j] + (kc + 2) * 64,
                        SW((kc + 2) % 3) + (j * 256 + wv * 64) * 8);
      }

      __builtin_amdgcn_s_setprio(1);
      #pragma unroll
      for (int mt = 0; mt < 4; mt++)
        #pragma unroll
        for (int nt = 0; nt < 4; nt++)
          acc[mt][nt] = __builtin_amdgcn_mfma_f32_16x16x32_bf16(
              wf[mt], pf[nt], acc[mt][nt], 0, 0, 0);
      __builtin_amdgcn_s_setprio(0);
    }
  }

  // ---- epilogue: per-wave LDS transpose -> dwordx4 full-line stores ----
  // All K-loop LDS reads must retire before patches overwrite slab/sW[0..1].
  __syncthreads();

  float* patch = (float*)smem + (size_t)wv * 4096;   // private 16 KB / wave

  // write acc (+bias) as patch[co_local][pr_local], 64x64
  #pragma unroll
  for (int mt = 0; mt < 4; mt++)
    #pragma unroll
    for (int nt = 0; nt < 4; nt++)
      #pragma unroll
      for (int r = 0; r < 4; r++)
        patch[(mt * 16 + q * 4 + r) * 64 + nt * 16 + ln] =
            acc[mt][nt][r] + bs[mt][r];

  // read back 16B/lane along pr, store 256B-contiguous dwordx4 runs
  int pr0 = (lane & 15) * 4;           // 0,4,...,60
  int cr  = lane >> 4;                 // 0..3
  int prg0 = r0 + wx * 64 + pr0;       // global pr of this lane's 4-run
  size_t ybase = (size_t)img * C_OUT * SPI + prg0;
  #pragma unroll
  for (int i = 0; i < 16; i++) {
    int co_l = i * 4 + cr;             // 0..63
    f32x4 v = *(const f32x4*)(patch + co_l * 64 + pr0);
    if (prg0 < SPI)                    // SPI%4==0 -> exact dwordx4 mask
      *(f32x4*)(y + ybase + (size_t)(wy * 64 + co_l) * SPI) = v;
  }
  #undef SW
}

extern "C" void kernel_launch(void* const* d_in, const int* in_sizes, int n_in,
                              void* d_out, int out_size, void* d_ws, size_t ws_size,
                              hipStream_t stream) {
  const float* x    = (const float*)d_in[0];
  const float* w    = (const float*)d_in[1];
  const float* bias = (const float*)d_in[2];
  float* y = (float*)d_out;

  u16* wtT = (u16*)d_ws;
  u16* xt  = (u16*)((char*)d_ws + (size_t)C_OUT * KTOT * sizeof(u16)); // +147456 B

  hipLaunchKernelGGL(convert_xw, dim3(HW_IN / 64, N_IMG + 1), dim3(256), 0, stream,
                     x, w, xt, wtT);
  hipLaunchKernelGGL(conv_gemm, dim3(NWG), dim3(256), 0, stream,
                     xt, wtT, bias, y);
}